// Round 6
// baseline (71.216 us; speedup 1.0000x reference)
//
#include <hip/hip_runtime.h>
#include <cfloat>

// Problem constants (fixed by the reference): B=8, N=4096, NUM_CLASS=13, C=3.
constexpr int Bb    = 8;
constexpr int Nn    = 4096;
constexpr int NC    = 13;
constexpr int BLOCK = 512;       // 8 waves = 2 i-groups x 4 j-quarters
constexpr int NG    = 4;         // B-fragments (i-subgroups of 32) per wave
constexpr int JQ    = 4;         // j-range split across waves
constexpr int ICH   = Nn / 256;  // 16 i-chunks of 256 per (dir,b)
constexpr int TILES = Nn / 32 / JQ;  // 32 j-tiles per quarter
// Grid = 2 dir * 8 b * 16 chunk = 256 blocks -> 1 block/CU, 2 waves/SIMD.
// Key change vs R4: one ds_read_b128 (A-fragment) now feeds 4 MFMAs
// (4 B-fragments/wave), cutting per-CU LDS reads 4x (was the bottleneck:
// 8 waves * 128 reads * ~12cyc = 5.1us; now ~1.3us, kernel ~VALU-bound).

typedef __attribute__((ext_vector_type(8)))  short          short8;
typedef __attribute__((ext_vector_type(8)))  unsigned short ushort8;
typedef __attribute__((ext_vector_type(16))) float          floatx16;

// fp32 -> bf16 round-to-nearest-even (bit trick; inputs are finite).
static __device__ inline unsigned short f2bf(float f) {
    unsigned u = __builtin_bit_cast(unsigned, f);
    return (unsigned short)((u + 0x7FFFu + ((u >> 16) & 1u)) >> 16);
}
static __device__ inline float bf2f(unsigned short h) {
    return __builtin_bit_cast(float, (unsigned)h << 16);
}

// LDS A-fragment per target point j: {yh0, yh1, yh2, h1, h2, 0, 0, 0} with
// h1+h2 ~= |yhat|^2 (two-term bf16 split of the fp32 value).
// B per (wave, g): lanes 0-31 = {-2xh0,-2xh1,-2xh2, 1, 1, 0,0,0}, lanes
// 32-63 = 0 (they feed k=8..15, which must not contribute; A's hi-lane rows
// are harmless duplicates). One v_mfma_f32_32x32x16_bf16 per (32-j tile, g)
// -> t(j,i) = yy - 2 x.y in fp32; v_min3 chains reduce 16 C-values/lane;
// shfl_xor(32) merges row halves; j-quarter partials merge via LDS.
// xx (rounded-x, consistent with B) is constant per i -> dropped from the
// min, added back in the block sum with the NLL seg gather (dir 0).
__global__ __launch_bounds__(BLOCK)
void criterion_fused_kernel(const float* __restrict__ seg_prob,
                            const int*   __restrict__ seg_label,
                            const float* __restrict__ point_rec,
                            const float* __restrict__ point,
                            float*       __restrict__ out) {
    __shared__ ushort8 ytile[Nn];               // 64 KB
    __shared__ float   cmin[BLOCK / 64][NG][32]; // 4 KB j-quarter partial mins
    __shared__ float   wsum[BLOCK / 64];

    const int blk   = blockIdx.x;
    const int chunk = blk & (ICH - 1);
    const int b     = (blk >> 4) & (Bb - 1);
    const int dir   = blk >> 7;
    const int t     = threadIdx.x;
    const int lane  = t & 63;
    const int wave  = t >> 6;
    const int l31   = lane & 31;
    const bool lo   = (lane < 32);
    const int igrp  = wave >> 2;   // 0..1 : which 128 i's
    const int jq    = wave & 3;    // 0..3 : which 1024 j's

    const float* __restrict__ xbase =
        (dir ? point : point_rec) + (size_t)(b * Nn + chunk * 256) * 3;
    const float* __restrict__ ybase =
        (dir ? point_rec : point) + (size_t)b * Nn * 3;

    // ---- stage the full Y row: 8 points per thread ----
    #pragma unroll
    for (int q = 0; q < Nn / BLOCK; ++q) {
        const int p = q * BLOCK + t;
        const float* yp = ybase + (size_t)p * 3;
        const unsigned short yh0 = f2bf(yp[0]);
        const unsigned short yh1 = f2bf(yp[1]);
        const unsigned short yh2 = f2bf(yp[2]);
        const float yf0 = bf2f(yh0), yf1 = bf2f(yh1), yf2 = bf2f(yh2);
        const float yy  = fmaf(yf2, yf2, fmaf(yf1, yf1, yf0 * yf0));
        const unsigned short h1 = f2bf(yy);
        const unsigned short h2 = f2bf(yy - bf2f(h1));
        ushort8 v;
        v[0] = yh0; v[1] = yh1; v[2] = yh2; v[3] = h1; v[4] = h2;
        v[5] = 0;   v[6] = 0;   v[7] = 0;
        ytile[p] = v;
    }

    // ---- 4 B fragments: this wave's 128 x-points ----
    short8 bfrag[NG];
    float  xx[NG];
    #pragma unroll
    for (int g = 0; g < NG; ++g) {
        const int    i_loc = igrp * 128 + g * 32 + l31;  // 0..255 in chunk
        const float* xp    = xbase + (size_t)i_loc * 3;
        const float  a0 = bf2f(f2bf(xp[0]));
        const float  a1 = bf2f(f2bf(xp[1]));
        const float  a2 = bf2f(f2bf(xp[2]));
        xx[g] = fmaf(a2, a2, fmaf(a1, a1, a0 * a0));
        ushort8 bu;
        bu[0] = lo ? f2bf(-2.0f * a0) : (unsigned short)0;
        bu[1] = lo ? f2bf(-2.0f * a1) : (unsigned short)0;
        bu[2] = lo ? f2bf(-2.0f * a2) : (unsigned short)0;
        bu[3] = lo ? (unsigned short)0x3F80 : (unsigned short)0;  // bf16 1.0
        bu[4] = lo ? (unsigned short)0x3F80 : (unsigned short)0;
        bu[5] = 0; bu[6] = 0; bu[7] = 0;
        bfrag[g] = __builtin_bit_cast(short8, bu);
    }

    floatx16 zc;
    #pragma unroll
    for (int q = 0; q < 16; ++q) zc[q] = 0.0f;

    __syncthreads();

    // ---- main loop: this wave's j-quarter, 1 A-read feeds 4 MFMAs ----
    float m[NG][4];
    #pragma unroll
    for (int g = 0; g < NG; ++g)
        #pragma unroll
        for (int q = 0; q < 4; ++q) m[g][q] = FLT_MAX;

    #pragma unroll 4
    for (int jt = 0; jt < TILES; ++jt) {
        const short8 af = __builtin_bit_cast(
            short8, ytile[(jq * TILES + jt) * 32 + l31]);
        #pragma unroll
        for (int g = 0; g < NG; ++g) {
            const floatx16 d =
                __builtin_amdgcn_mfma_f32_32x32x16_bf16(af, bfrag[g], zc, 0, 0, 0);
            m[g][0] = fminf(fminf(d[0],  d[1]),  m[g][0]);   // v_min3 each
            m[g][1] = fminf(fminf(d[2],  d[3]),  m[g][1]);
            m[g][2] = fminf(fminf(d[4],  d[5]),  m[g][2]);
            m[g][3] = fminf(fminf(d[6],  d[7]),  m[g][3]);
            m[g][0] = fminf(fminf(d[8],  d[9]),  m[g][0]);
            m[g][1] = fminf(fminf(d[10], d[11]), m[g][1]);
            m[g][2] = fminf(fminf(d[12], d[13]), m[g][2]);
            m[g][3] = fminf(fminf(d[14], d[15]), m[g][3]);
        }
    }

    // Per-lane min covers 16 of 32 rows; lane^32 has the rest; then publish
    // this wave's j-quarter min for its 128 columns.
    #pragma unroll
    for (int g = 0; g < NG; ++g) {
        float mm = fminf(fminf(m[g][0], m[g][1]), fminf(m[g][2], m[g][3]));
        mm = fminf(mm, __shfl_xor(mm, 32, 64));
        if (lo) cmin[wave][g][l31] = mm;
    }
    __syncthreads();

    // ---- epilogue: jq==0 waves merge the 4 j-quarters, add xx & seg ----
    float v = 0.0f;
    if (jq == 0 && lo) {
        #pragma unroll
        for (int g = 0; g < NG; ++g) {
            float mg = cmin[igrp * 4 + 0][g][l31];
            mg = fminf(mg, cmin[igrp * 4 + 1][g][l31]);
            mg = fminf(mg, cmin[igrp * 4 + 2][g][l31]);
            mg = fminf(mg, cmin[igrp * 4 + 3][g][l31]);
            v += mg + xx[g];
            if (dir == 0) {
                const int gi = b * Nn + chunk * 256 + igrp * 128 + g * 32 + l31;
                v -= seg_prob[(size_t)gi * NC + (size_t)seg_label[gi]];
            }
        }
    }

    // Block reduction: wave-64 shuffle, then across the 8 waves via LDS.
    for (int off = 32; off > 0; off >>= 1)
        v += __shfl_down(v, off, 64);
    if ((t & 63) == 0) wsum[t >> 6] = v;
    __syncthreads();
    if (t == 0) {
        float s = 0.0f;
        #pragma unroll
        for (int w = 0; w < BLOCK / 64; ++w) s += wsum[w];
        atomicAdd(out, s * (1.0f / (Bb * Nn)));
    }
}

extern "C" void kernel_launch(void* const* d_in, const int* in_sizes, int n_in,
                              void* d_out, int out_size, void* d_ws, size_t ws_size,
                              hipStream_t stream) {
    const float* seg_prob  = (const float*)d_in[0];
    const int*   seg_label = (const int*)d_in[1];
    const float* point_rec = (const float*)d_in[2];
    const float* point     = (const float*)d_in[3];
    float*       out       = (float*)d_out;

    hipMemsetAsync(out, 0, sizeof(float), stream);
    criterion_fused_kernel<<<dim3(2 * Bb * ICH), dim3(BLOCK), 0, stream>>>(
        seg_prob, seg_label, point_rec, point, out);
}